// Round 12
// baseline (413.802 us; speedup 1.0000x reference)
//
#include <hip/hip_runtime.h>
#include <hip/hip_cooperative_groups.h>
#include <hip/hip_bf16.h>

namespace cg = cooperative_groups;

// ---------------- types ----------------
typedef __bf16 bf16x8 __attribute__((ext_vector_type(8)));
typedef __bf16 bf16x4 __attribute__((ext_vector_type(4)));
typedef float  f32x4  __attribute__((ext_vector_type(4)));

__device__ __forceinline__ __bf16 to_bf16(float f) {
    __hip_bfloat16 h = __float2bfloat16(f);
    return *reinterpret_cast<__bf16*>(&h);
}

__device__ __forceinline__ f32x4 mfma32(bf16x8 a, bf16x8 b, f32x4 c) {
    return __builtin_amdgcn_mfma_f32_16x16x32_bf16(a, b, c, 0, 0, 0);
}
__device__ __forceinline__ f32x4 mfma16(bf16x4 a, bf16x4 b, f32x4 c) {
#if __has_builtin(__builtin_amdgcn_mfma_f32_16x16x16_bf16)
    return __builtin_amdgcn_mfma_f32_16x16x16_bf16(a, b, c, 0, 0, 0);
#else
    typedef short s16x4 __attribute__((ext_vector_type(4)));
    return __builtin_amdgcn_mfma_f32_16x16x16bf16_1k(
        __builtin_bit_cast(s16x4, a), __builtin_bit_cast(s16x4, b), c, 0, 0, 0);
#endif
}

__device__ __forceinline__ void gload_lds16(const __bf16* g, __bf16* l) {
    __builtin_amdgcn_global_load_lds(
        (const __attribute__((address_space(1))) void*)g,
        (__attribute__((address_space(3))) void*)l, 16, 0, 0);
}

// constants: B=2, L=2048, DIM=1024, H=16, KVH=4, HD=64, REP=4
// Single cooperative kernel, 4 phases separated by grid-wide syncs:
//   P0 weight transposes (2560 32x32 tiles) + RoPE table
//   PA QKV GEMM + RMSNorm + RoPE + layout (384 work items)
//   PB flash attention (512 work items)
//   PC output projection GEMM (512 work items)
// GEMM LDS: rows of 64 bf16; 16B chunk slot s holds global chunk s^(row&7)
// (conflict-free ds_read_b128; gload dest linear, source pre-swizzled).

__global__ __launch_bounds__(512, 4) void fused_k(
        const float* __restrict__ X,  const float* __restrict__ wq,
        const float* __restrict__ wk, const float* __restrict__ wv,
        const float* __restrict__ wo, const float* __restrict__ gq,
        const float* __restrict__ gk,
        __bf16* __restrict__ WqkvT, __bf16* __restrict__ WoT,
        float2* __restrict__ rtab,
        __bf16* __restrict__ Qb, __bf16* __restrict__ Kbl,
        __bf16* __restrict__ Vt, __bf16* __restrict__ aout,
        float* __restrict__ out) {
    extern __shared__ char smem_raw[];
    __shared__ float ssp[4][128];
    cg::grid_group gg = cg::this_grid();
    const int tid = threadIdx.x;
    const int nb = gridDim.x;

    // ---------------- phase 0: transposes + rope ----------------
    {
        float* scr = (float*)smem_raw;                 // 2 x 32x36 f32
        int sub = tid >> 8, t8 = tid & 255;
        int row = t8 >> 3, c4 = t8 & 7;
        float* my = scr + sub * 1152;
        for (int base2 = blockIdx.x * 2; base2 < 2560; base2 += nb * 2) {
            int tile = base2 + sub;
            const float* src = wq; __bf16* dst = WqkvT; int N = 1024; int idx = tile;
            if (tile >= 1536)      { src = wo; dst = WoT;                       N = 1024; idx = tile - 1536; }
            else if (tile >= 1280) { src = wv; dst = WqkvT + (size_t)1280*1024; N = 256;  idx = tile - 1280; }
            else if (tile >= 1024) { src = wk; dst = WqkvT + (size_t)1024*1024; N = 256;  idx = tile - 1024; }
            int k0 = (idx & 31) * 32, n0 = (idx >> 5) * 32;
            __syncthreads();
            *(f32x4*)&my[row * 36 + c4 * 4] =
                *(const f32x4*)(src + (size_t)(k0 + row) * N + n0 + c4 * 4);
            __syncthreads();
            bf16x4 v;
#pragma unroll
            for (int j = 0; j < 4; ++j) v[j] = to_bf16(my[(c4 * 4 + j) * 36 + row]);
            *(bf16x4*)&dst[(size_t)(n0 + row) * 1024 + k0 + c4 * 4] = v;
        }
        for (int gid = blockIdx.x * 512 + tid; gid < 65536; gid += nb * 512) {
            int pos = gid >> 5, f = gid & 31;
            float ex = (float)(2 * f) * (1.0f / 64.0f);
            float invf = expf(-ex * 9.210340371976184f);
            float ang = (float)pos * invf;
            rtab[gid] = make_float2(cosf(ang), sinf(ang));
        }
    }
    __threadfence();
    gg.sync();

    // ---------------- phase A: QKV GEMM (384 items) ----------------
    for (int wb = blockIdx.x; wb < 384; wb += nb) {
        __bf16* smem = (__bf16*)smem_raw;
        int m0 = (wb & 31) * 128, n0 = (wb >> 5) * 128;
        int wid = tid >> 6, lane = tid & 63;
        int wm = (wid & 1) * 64, wn = (wid >> 1) * 32;
        int lm = lane & 15, qd = lane >> 4;
        int arow = tid >> 3, aslot = tid & 7;
        int asrc = aslot ^ (arow & 7);
        f32x4 acc[4][2] = {};
        f32x4 areg[4];

        auto A_LOAD = [&](int t) {
            const float* ap = X + (size_t)(m0 + arow) * 1024 + t * 64 + asrc * 8;
            areg[0] = *(const f32x4*)ap;
            areg[1] = *(const f32x4*)(ap + 4);
            const float* ap2 = ap + (size_t)64 * 1024;
            areg[2] = *(const f32x4*)ap2;
            areg[3] = *(const f32x4*)(ap2 + 4);
        };
        auto A_WRITE = [&](int bsel) {
            __bf16* ab = smem + bsel * 16384;
            bf16x8 w0, w1;
#pragma unroll
            for (int j = 0; j < 4; ++j) {
                w0[j] = to_bf16(areg[0][j]); w0[4 + j] = to_bf16(areg[1][j]);
                w1[j] = to_bf16(areg[2][j]); w1[4 + j] = to_bf16(areg[3][j]);
            }
            *(bf16x8*)&ab[arow * 64 + aslot * 8] = w0;
            *(bf16x8*)&ab[(arow + 64) * 64 + aslot * 8] = w1;
        };
        auto B_GLOAD = [&](int bsel, int t) {
            __bf16* base = smem + bsel * 16384 + 8192;
#pragma unroll
            for (int r = 0; r < 2; ++r) {
                int row = r * 64 + (tid >> 3);
                int c8 = (tid & 7) ^ (row & 7);
                gload_lds16(WqkvT + (size_t)(n0 + row) * 1024 + t * 64 + c8 * 8,
                            base + r * 4096 + wid * 512);
            }
        };

        A_LOAD(0);
        B_GLOAD(0, 0);
        asm volatile("s_waitcnt vmcnt(2)" ::: "memory");
        A_WRITE(0);

        for (int t = 0; t < 16; ++t) {
            if (t + 1 < 16) {
                A_LOAD(t + 1);
                B_GLOAD((t + 1) & 1, t + 1);
                asm volatile("s_waitcnt vmcnt(6)" ::: "memory");
            } else {
                asm volatile("s_waitcnt vmcnt(0)" ::: "memory");
            }
            asm volatile("s_waitcnt lgkmcnt(0)" ::: "memory");
            __builtin_amdgcn_s_barrier();
            __builtin_amdgcn_sched_barrier(0);
            const __bf16* cA = smem + (t & 1) * 16384;
            const __bf16* cB = cA + 8192;
#pragma unroll
            for (int kh = 0; kh < 2; ++kh) {
                bf16x8 af[4], bfr[2];
#pragma unroll
                for (int t4 = 0; t4 < 4; ++t4) {
                    int row = wm + t4 * 16 + lm;
                    af[t4] = *(const bf16x8*)&cA[row * 64 + (((kh * 4 + qd) ^ (row & 7)) * 8)];
                }
#pragma unroll
                for (int j = 0; j < 2; ++j) {
                    int col = wn + j * 16 + lm;
                    bfr[j] = *(const bf16x8*)&cB[col * 64 + (((kh * 4 + qd) ^ (col & 7)) * 8)];
                }
#pragma unroll
                for (int ti = 0; ti < 4; ++ti)
#pragma unroll
                    for (int tj = 0; tj < 2; ++tj)
                        acc[ti][tj] = mfma32(af[ti], bfr[tj], acc[ti][tj]);
            }
            if (t + 1 < 16) {
                asm volatile("s_waitcnt vmcnt(2)" ::: "memory");
                A_WRITE((t + 1) & 1);
            }
            asm volatile("s_waitcnt lgkmcnt(0)" ::: "memory");
            __builtin_amdgcn_s_barrier();
        }

        int head0 = n0 >> 6;
        int quad = wid >> 1;
        int chead = wn & 63;

        if (head0 < 20) {
            int head = head0 + (quad >> 1);
            bool isq = head < 16;
            const float* gvec = isq ? gq : gk;
            float gam[2];
#pragma unroll
            for (int tj = 0; tj < 2; ++tj) gam[tj] = gvec[chead + tj * 16 + lm];
#pragma unroll
            for (int ti = 0; ti < 4; ++ti)
#pragma unroll
                for (int r = 0; r < 4; ++r) {
                    float sq = acc[ti][0][r] * acc[ti][0][r] + acc[ti][1][r] * acc[ti][1][r];
                    sq += __shfl_xor(sq, 1);
                    sq += __shfl_xor(sq, 2);
                    sq += __shfl_xor(sq, 4);
                    sq += __shfl_xor(sq, 8);
                    if (lm == 0) ssp[quad][wm + ti * 16 + qd * 4 + r] = sq;
                }
            __syncthreads();
#pragma unroll
            for (int ti = 0; ti < 4; ++ti)
#pragma unroll
                for (int r = 0; r < 4; ++r) {
                    int row = wm + ti * 16 + qd * 4 + r;
                    int t = m0 + row;
                    int pos = t & 2047, bb = t >> 11;
                    float ss = ssp[quad][row] + ssp[quad ^ 1][row];
                    float scale = rsqrtf(ss * (1.0f / 64.0f) + 1e-6f);
#pragma unroll
                    for (int tj = 0; tj < 2; ++tj) {
                        int cw = chead + tj * 16 + lm;
                        float v = acc[ti][tj][r] * scale * gam[tj];
                        float2 cs = rtab[pos * 32 + (cw >> 1)];
                        float pv = __shfl_xor(v, 1);
                        float outv = (cw & 1) ? (pv * cs.y + v * cs.x) : (v * cs.x - pv * cs.y);
                        if (isq) {
                            int kvh = head >> 2, h4 = head & 3;
                            size_t off = (((((size_t)bb * 4 + kvh) * 128 + (pos >> 4)) * 4 + h4) * 16
                                          + (pos & 15)) * 64 + cw;
                            Qb[off] = to_bf16(outv * 0.125f);
                        } else {
                            int kvg = head - 16;
                            Kbl[(((size_t)bb * 4 + kvg) * 2048 + pos) * 64 + cw] = to_bf16(outv);
                        }
                    }
                }
            __syncthreads();
        } else {
            __bf16* tvh = smem + (quad >> 1) * 8704;
            int bb = m0 >> 11, pos0 = m0 & 2047;
#pragma unroll
            for (int ti = 0; ti < 4; ++ti)
#pragma unroll
                for (int tj = 0; tj < 2; ++tj)
#pragma unroll
                    for (int r = 0; r < 4; ++r) {
                        int row = wm + ti * 16 + qd * 4 + r;
                        int cw = chead + tj * 16 + lm;
                        tvh[cw * 136 + row] = to_bf16(acc[ti][tj][r]);
                    }
            __syncthreads();
            int hh = tid >> 8, t8 = tid & 255;
            int kvg = head0 + hh - 20;
            size_t gg2 = (size_t)bb * 4 + kvg;
            const __bf16* tvr = smem + hh * 8704;
#pragma unroll
            for (int p = 0; p < 4; ++p) {
                int d = p * 16 + (t8 >> 4);
                int tok = (t8 & 15) * 8;
                bf16x8 vvv = *(const bf16x8*)&tvr[d * 136 + tok];
                *(bf16x8*)(Vt + (gg2 * 64 + d) * 2048 + pos0 + tok) = vvv;
            }
            __syncthreads();
        }
    }
    __threadfence();
    gg.sync();

    // ---------------- phase B: flash attention (512 items) ----------------
    for (int wb = blockIdx.x; wb < 512; wb += nb) {
        __bf16* smem = (__bf16*)smem_raw;   // Kt[2]@0, Vl[2]@8192, 32KB total
        int wid = tid >> 6, lane = tid & 63;
        int l15 = lane & 15, quad = lane >> 4;
        int qb = wb & 63, kvh = (wb >> 6) & 3, b = wb >> 8;
        int qg = wid >> 2;
        int h4 = wid & 3;
        int iw0 = qb * 32;
        int iw = iw0 + qg * 16;
        int g = b * 4 + kvh;
        int h = kvh * 4 + h4;
        int e7 = l15 & 7;

        int qbi = qb * 2 + qg;
        const __bf16* qp = Qb + ((((size_t)g * 128 + qbi) * 4 + h4) * 16 + l15) * 64 + quad * 8;
        bf16x8 qf0 = *(const bf16x8*)qp;
        bf16x8 qf1 = *(const bf16x8*)(qp + 32);

        int ts = (iw0 - 256) >> 6; if (ts < 1) ts = 1;
        int tmaxb = (iw0 + 31) >> 6;
        int n_all = (tmaxb >= ts) ? (tmaxb - ts + 2) : 1;
        int tmaxw = (iw + 15) >> 6;

        const __bf16* Kg = Kbl + (size_t)g * 2048 * 64;
        const __bf16* Vg = Vt + (size_t)g * 64 * 2048;

        int r0 = tid >> 3, c0 = tid & 7;
        int kl = r0 * 64 + ((c0 ^ (r0 & 7)) * 8);

        bf16x8 kr, vr;
        auto stage_load = [&](int tt) {
            kr = *(const bf16x8*)(Kg + (size_t)tt * 64 * 64 + r0 * 64 + c0 * 8);
            vr = *(const bf16x8*)(Vg + (size_t)r0 * 2048 + tt * 64 + c0 * 8);
        };
        auto stage_write = [&](int buf) {
            *(bf16x8*)&smem[buf * 4096 + kl] = kr;
            *(bf16x8*)&smem[8192 + buf * 4096 + kl] = vr;
        };

        stage_load(0);
        stage_write(0);

        f32x4 o[4] = {};
        float mr = -1e30f, lrp = 0.f;
        int iq = iw + l15;

        for (int idx = 0; idx < n_all; ++idx) {
            int tt = (idx == 0) ? 0 : ts + idx - 1;
            if (idx + 1 < n_all) stage_load(ts + idx);
            __syncthreads();
            int buf = idx & 1;

            f32x4 s[4] = {};
#pragma unroll
            for (int nt = 0; nt < 4; ++nt) {
                const __bf16* kp = &smem[buf * 4096 + (nt * 16 + l15) * 64];
                bf16x8 k0 = *(const bf16x8*)(kp + ((quad ^ e7) * 8));
                bf16x8 k1 = *(const bf16x8*)(kp + (((quad + 4) ^ e7) * 8));
                s[nt] = mfma32(k0, qf0, s[nt]);
                s[nt] = mfma32(k1, qf1, s[nt]);
            }

            bool need_mask = (tt >= tmaxw) || (tt >= 1 && tt * 64 < iw + 15 - 256);
            if (need_mask) {
#pragma unroll
                for (int nt = 0; nt < 4; ++nt)
#pragma unroll
                    for (int r = 0; r < 4; ++r) {
                        int j = tt * 64 + nt * 16 + quad * 4 + r;
                        bool valid = (j <= iq) && ((j >= iq - 256) || (j < 64));
                        s[nt][r] = valid ? s[nt][r] : -1e30f;
                    }
            }

            float mx = -1e30f;
#pragma unroll
            for (int nt = 0; nt < 4; ++nt)
#pragma unroll
                for (int r = 0; r < 4; ++r) mx = fmaxf(mx, s[nt][r]);
            mx = fmaxf(mx, __shfl_xor(mx, 16));
            mx = fmaxf(mx, __shfl_xor(mx, 32));
            float mn = fmaxf(mr, mx);
            float alpha = __expf(mr - mn);
            mr = mn;

            float ps = 0.f;
            bf16x4 pb[4];
#pragma unroll
            for (int nt = 0; nt < 4; ++nt)
#pragma unroll
                for (int r = 0; r < 4; ++r) {
                    float pv = __expf(s[nt][r] - mn);
                    ps += pv;
                    pb[nt][r] = to_bf16(pv);
                }
            lrp = lrp * alpha + ps;

#pragma unroll
            for (int dt = 0; dt < 4; ++dt) {
                o[dt] *= alpha;
                const __bf16* vp = &smem[8192 + buf * 4096 + (dt * 16 + l15) * 64];
#pragma unroll
                for (int nt = 0; nt < 4; ++nt) {
                    int c8 = 2 * nt + (quad >> 1);
                    bf16x4 va = *(const bf16x4*)(vp + ((c8 ^ e7) * 8) + (quad & 1) * 4);
                    o[dt] = mfma16(va, pb[nt], o[dt]);
                }
            }

            if (idx + 1 < n_all) stage_write((idx + 1) & 1);
        }

        lrp += __shfl_xor(lrp, 16);
        lrp += __shfl_xor(lrp, 32);
        float inv = 1.f / lrp;
        __syncthreads();
        __bf16* pr = smem + wid * 1024;
#pragma unroll
        for (int dt = 0; dt < 4; ++dt)
#pragma unroll
            for (int r = 0; r < 4; ++r) {
                int e = dt * 16 + quad * 4 + r;
                int c8 = e >> 3;
                pr[l15 * 64 + ((c8 ^ e7) * 8) + (e & 7)] = to_bf16(o[dt][r] * inv);
            }
        bf16x8 o0 = *(const bf16x8*)(pr + l15 * 64 + (((2 * quad) ^ e7) * 8));
        bf16x8 o1 = *(const bf16x8*)(pr + l15 * 64 + (((2 * quad + 1) ^ e7) * 8));
        __bf16* op = aout + ((size_t)b * 2048 + iw + l15) * 1024 + h * 64 + quad * 16;
        *(bf16x8*)op = o0;
        *(bf16x8*)(op + 8) = o1;
        __syncthreads();
    }
    __threadfence();
    gg.sync();

    // ---------------- phase C: output projection (512 items) ----------------
    for (int wb = blockIdx.x; wb < 512; wb += nb) {
        __bf16* smem = (__bf16*)smem_raw;
        int m0 = (wb & 31) * 128, n0 = (wb >> 5) * 64;
        int wid = tid >> 6, lane = tid & 63;
        int wm = (wid & 3) * 32, wn = (wid >> 2) * 32;
        int lm = lane & 15, qd = lane >> 4;
        f32x4 acc[2][2] = {};
        auto STAGE = [&](int bsel, int t) {
            __bf16* base = smem + bsel * 12288;
#pragma unroll
            for (int r = 0; r < 2; ++r) {
                int row = r * 64 + (tid >> 3);
                int c8 = (tid & 7) ^ (row & 7);
                gload_lds16(aout + (size_t)(m0 + row) * 1024 + t * 64 + c8 * 8,
                            base + r * 4096 + wid * 512);
            }
            {
                int row = tid >> 3;
                int c8 = (tid & 7) ^ (row & 7);
                gload_lds16(WoT + (size_t)(n0 + row) * 1024 + t * 64 + c8 * 8,
                            base + 8192 + wid * 512);
            }
        };
        STAGE(0, 0);
        for (int t = 0; t < 16; ++t) {
            if (t + 1 < 16) {
                STAGE((t + 1) & 1, t + 1);
                asm volatile("s_waitcnt vmcnt(3)" ::: "memory");
            } else {
                asm volatile("s_waitcnt vmcnt(0)" ::: "memory");
            }
            __builtin_amdgcn_s_barrier();
            __builtin_amdgcn_sched_barrier(0);
            const __bf16* cA = smem + (t & 1) * 12288;
            const __bf16* cB = cA + 8192;
#pragma unroll
            for (int kh = 0; kh < 2; ++kh) {
                bf16x8 af[2], bfr[2];
#pragma unroll
                for (int i = 0; i < 2; ++i) {
                    int row = wm + i * 16 + lm;
                    af[i] = *(const bf16x8*)&cA[row * 64 + (((kh * 4 + qd) ^ (row & 7)) * 8)];
                    int col = wn + i * 16 + lm;
                    bfr[i] = *(const bf16x8*)&cB[col * 64 + (((kh * 4 + qd) ^ (col & 7)) * 8)];
                }
#pragma unroll
                for (int ti = 0; ti < 2; ++ti)
#pragma unroll
                    for (int tj = 0; tj < 2; ++tj)
                        acc[ti][tj] = mfma32(af[ti], bfr[tj], acc[ti][tj]);
            }
            asm volatile("s_waitcnt lgkmcnt(0)" ::: "memory");
            __builtin_amdgcn_s_barrier();
        }
#pragma unroll
        for (int ti = 0; ti < 2; ++ti)
#pragma unroll
            for (int tj = 0; tj < 2; ++tj)
#pragma unroll
                for (int r = 0; r < 4; ++r) {
                    int row = m0 + wm + ti * 16 + qd * 4 + r;
                    int col = n0 + wn + tj * 16 + lm;
                    out[(size_t)row * 1024 + col] = acc[ti][tj][r];
                }
    }
}

// ---------------- launch ----------------
extern "C" void kernel_launch(void* const* d_in, const int* in_sizes, int n_in,
                              void* d_out, int out_size, void* d_ws, size_t ws_size,
                              hipStream_t stream) {
    const float* x  = (const float*)d_in[0];
    const float* wq = (const float*)d_in[1];
    const float* wk = (const float*)d_in[2];
    const float* wv = (const float*)d_in[3];
    const float* wo = (const float*)d_in[4];
    const float* gq = (const float*)d_in[5];
    const float* gk = (const float*)d_in[6];
    float* out = (float*)d_out;

    char* ws = (char*)d_ws;
    __bf16*  WqkvT = (__bf16*)ws;                        //  3145728 B
    __bf16*  WoT   = (__bf16*)(ws + 3145728);            //  2097152 B
    __bf16*  aout  = (__bf16*)(ws + 5242880);            //  8388608 B
    __bf16*  Kbl   = (__bf16*)(ws + 13631488);           //  2097152 B
    __bf16*  Vt    = (__bf16*)(ws + 15728640);           //  2097152 B
    __bf16*  Qb    = (__bf16*)(ws + 17825792);           //  8388608 B
    float2*  rtab  = (float2*)(ws + 26214400);           //   524288 B -> total 26738688

    static int coop_grid = 0;
    if (coop_grid == 0) {
        int bpc = 0;
        hipOccupancyMaxActiveBlocksPerMultiprocessor(&bpc, fused_k, 512, 65536);
        hipDeviceProp_t props;
        int dev = 0;
        hipGetDevice(&dev);
        hipGetDeviceProperties(&props, dev);
        long g = (long)bpc * (long)props.multiProcessorCount;
        if (g < 1) g = 1;
        if (g > 512) g = 512;
        coop_grid = (int)g;
    }

    void* args[] = {(void*)&x, (void*)&wq, (void*)&wk, (void*)&wv, (void*)&wo,
                    (void*)&gq, (void*)&gk, (void*)&WqkvT, (void*)&WoT, (void*)&rtab,
                    (void*)&Qb, (void*)&Kbl, (void*)&Vt, (void*)&aout, (void*)&out};
    hipLaunchCooperativeKernel((void*)fused_k, dim3(coop_grid), dim3(512),
                               args, 65536, stream);
}

// Round 14
// 136.051 us; speedup vs baseline: 3.0415x; 3.0415x over previous
//
#include <hip/hip_runtime.h>
#include <hip/hip_bf16.h>

// ---------------- types ----------------
typedef __bf16 bf16x8 __attribute__((ext_vector_type(8)));
typedef __bf16 bf16x4 __attribute__((ext_vector_type(4)));
typedef float  f32x4  __attribute__((ext_vector_type(4)));
typedef short  s16x4  __attribute__((ext_vector_type(4)));

__device__ __forceinline__ __bf16 to_bf16(float f) {
    __hip_bfloat16 h = __float2bfloat16(f);
    return *reinterpret_cast<__bf16*>(&h);
}

__device__ __forceinline__ f32x4 mfma32(bf16x8 a, bf16x8 b, f32x4 c) {
    return __builtin_amdgcn_mfma_f32_16x16x32_bf16(a, b, c, 0, 0, 0);
}
// 16x16x16 bf16 MFMA (PV): S^T C-layout == B-layout, so P^T feeds directly
__device__ __forceinline__ f32x4 mfma16(bf16x4 a, bf16x4 b, f32x4 c) {
#if __has_builtin(__builtin_amdgcn_mfma_f32_16x16x16_bf16)
    return __builtin_amdgcn_mfma_f32_16x16x16_bf16(a, b, c, 0, 0, 0);
#else
    return __builtin_amdgcn_mfma_f32_16x16x16bf16_1k(
        __builtin_bit_cast(s16x4, a), __builtin_bit_cast(s16x4, b), c, 0, 0, 0);
#endif
}

// async global->LDS, 16B per lane; lds ptr must be wave-uniform (GEMM only)
__device__ __forceinline__ void gload_lds16(const __bf16* g, __bf16* l) {
    __builtin_amdgcn_global_load_lds(
        (const __attribute__((address_space(1))) void*)g,
        (__attribute__((address_space(3))) void*)l, 16, 0, 0);
}

// constants: B=2, L=2048, DIM=1024, H=16, KVH=4, HD=64, REP=4
// GEMM LDS layout (both kernels): per side, rows of 64 bf16 (128B); the 8
// 16B-chunks of each row are XOR-swizzled: LDS slot s holds global chunk
// s ^ (row&7).  ds_read_b128 by 16 lanes at consecutive rows then covers all
// 8 bank-quads per 8-lane phase -> conflict-free (attn-verified T2 pattern).
// gload_lds16 keeps a LINEAR lds dest; the global SOURCE is pre-swizzled.

// ------- prep: wq/wk/wv transposes (vectorized) + RoPE table ---------------
__global__ __launch_bounds__(256) void prep_k(const float* __restrict__ wq,
                                              const float* __restrict__ wk,
                                              const float* __restrict__ wv,
                                              __bf16* __restrict__ WqkvT,
                                              float2* __restrict__ rope_tab) {
    int b = blockIdx.x, tid = threadIdx.x;
    if (b >= 1536) {
        int idx = (b - 1536) * 256 + tid;
        int pos = idx >> 5, f = idx & 31;
        float ex = (float)(2 * f) * (1.0f / 64.0f);
        float invf = expf(-ex * 9.210340371976184f);
        float ang = (float)pos * invf;
        rope_tab[idx] = make_float2(cosf(ang), sinf(ang));
        return;
    }
    __shared__ float tile[32][36];
    const float* src; __bf16* dst; int N, idx;
    if (b < 1024)      { src = wq; dst = WqkvT;                        N = 1024; idx = b; }
    else if (b < 1280) { src = wk; dst = WqkvT + (size_t)1024 * 1024;  N = 256;  idx = b - 1024; }
    else               { src = wv; dst = WqkvT + (size_t)1280 * 1024;  N = 256;  idx = b - 1280; }
    int k0 = (idx & 31) * 32, n0 = (idx >> 5) * 32;
    int row = tid >> 3, c4 = tid & 7;
    *(f32x4*)&tile[row][c4 * 4] = *(const f32x4*)(src + (size_t)(k0 + row) * N + n0 + c4 * 4);
    __syncthreads();
    bf16x4 v;
#pragma unroll
    for (int j = 0; j < 4; ++j) v[j] = to_bf16(tile[c4 * 4 + j][row]);
    *(bf16x4*)&dst[(size_t)(n0 + row) * 1024 + k0 + c4 * 4] = v;
}

// ------- fused QKV GEMM (512 thr, 8 waves, swizzled LDS) + RMSNorm + RoPE
//         + layout write + WoT transpose (y>=12) ----------------------------
// Wave tile 64x32 (2m x 4n), acc[4][2]. A reg-staged from f32 x (cast in reg,
// ds_write_b128 to swizzled slot); B via gload_lds16 with pre-swizzled source.
// LDS/buf: A 8192 + B 8192 bf16 = 32KB; x2 buffers = 64KB dynamic.
__global__ __launch_bounds__(512, 4) void gemmqkv_k(const float* __restrict__ X,
                                                    const __bf16* __restrict__ BT,
                                                    const float2* __restrict__ rope_tab,
                                                    const float* __restrict__ gq,
                                                    const float* __restrict__ gk,
                                                    const float* __restrict__ wo,
                                                    __bf16* __restrict__ Qb,
                                                    __bf16* __restrict__ Kbl,
                                                    __bf16* __restrict__ Vt,
                                                    __bf16* __restrict__ WoT) {
    extern __shared__ char smem_raw[];
    int tid = threadIdx.x;
    if (blockIdx.y >= 12) {
        // WoT transpose: 128 blocks x 8 tiles of 32x32 (vectorized, 512 thr)
        float* scr = (float*)smem_raw;                 // [2][32*36]
        int bidT = (blockIdx.y - 12) * 32 + blockIdx.x;
        int sub = tid >> 8, t8 = tid & 255;
        int row = t8 >> 3, c4 = t8 & 7;
        float* my = scr + sub * 1152;
#pragma unroll
        for (int r = 0; r < 4; ++r) {
            int tile = bidT * 8 + r * 2 + sub;
            int k0 = (tile & 31) * 32, n0t = (tile >> 5) * 32;
            __syncthreads();
            *(f32x4*)&my[row * 36 + c4 * 4] =
                *(const f32x4*)(wo + (size_t)(k0 + row) * 1024 + n0t + c4 * 4);
            __syncthreads();
            bf16x4 v;
#pragma unroll
            for (int j = 0; j < 4; ++j) v[j] = to_bf16(my[(c4 * 4 + j) * 36 + row]);
            *(bf16x4*)&WoT[(size_t)(n0t + row) * 1024 + k0 + c4 * 4] = v;
        }
        return;
    }
    __shared__ float ssp[4][128];
    __bf16* smem = (__bf16*)smem_raw;
    int m0 = blockIdx.x * 128, n0 = blockIdx.y * 128;
    int wid = tid >> 6, lane = tid & 63;
    int wm = (wid & 1) * 64, wn = (wid >> 1) * 32;
    int lm = lane & 15, qd = lane >> 4;
    // A staging: 2 chunks/thread, rows (tid>>3) and (tid>>3)+64, slot tid&7.
    int arow = tid >> 3, aslot = tid & 7;
    int asrc = aslot ^ (arow & 7);               // same for row and row+64
    f32x4 acc[4][2] = {};
    f32x4 areg[4];

    auto A_LOAD = [&](int t) {
        const float* ap = X + (size_t)(m0 + arow) * 1024 + t * 64 + asrc * 8;
        areg[0] = *(const f32x4*)ap;
        areg[1] = *(const f32x4*)(ap + 4);
        const float* ap2 = ap + (size_t)64 * 1024;
        areg[2] = *(const f32x4*)ap2;
        areg[3] = *(const f32x4*)(ap2 + 4);
    };
    auto A_WRITE = [&](int bsel) {
        __bf16* ab = smem + bsel * 16384;
        bf16x8 w0, w1;
#pragma unroll
        for (int j = 0; j < 4; ++j) {
            w0[j] = to_bf16(areg[0][j]); w0[4 + j] = to_bf16(areg[1][j]);
            w1[j] = to_bf16(areg[2][j]); w1[4 + j] = to_bf16(areg[3][j]);
        }
        *(bf16x8*)&ab[arow * 64 + aslot * 8] = w0;
        *(bf16x8*)&ab[(arow + 64) * 64 + aslot * 8] = w1;
    };
    auto B_GLOAD = [&](int bsel, int t) {
        __bf16* base = smem + bsel * 16384 + 8192;
#pragma unroll
        for (int r = 0; r < 2; ++r) {
            int row = r * 64 + (tid >> 3);
            int c8 = (tid & 7) ^ (row & 7);
            gload_lds16(BT + (size_t)(n0 + row) * 1024 + t * 64 + c8 * 8,
                        base + r * 4096 + wid * 512);
        }
    };

    // prologue: A(0) 4 flat loads, B(0) 2 gloads
    A_LOAD(0);
    B_GLOAD(0, 0);
    asm volatile("s_waitcnt vmcnt(2)" ::: "memory");   // A(0) regs ready
    A_WRITE(0);

    for (int t = 0; t < 16; ++t) {
        if (t + 1 < 16) {
            A_LOAD(t + 1);                             // 4 vm
            B_GLOAD((t + 1) & 1, t + 1);               // 2 vm
            asm volatile("s_waitcnt vmcnt(6)" ::: "memory");  // tile t complete
        } else {
            asm volatile("s_waitcnt vmcnt(0)" ::: "memory");
        }
        asm volatile("s_waitcnt lgkmcnt(0)" ::: "memory");    // A(t) ds_writes done
        __builtin_amdgcn_s_barrier();
        __builtin_amdgcn_sched_barrier(0);
        const __bf16* cA = smem + (t & 1) * 16384;
        const __bf16* cB = cA + 8192;
#pragma unroll
        for (int kh = 0; kh < 2; ++kh) {
            bf16x8 af[4], bfr[2];
#pragma unroll
            for (int t4 = 0; t4 < 4; ++t4) {
                int row = wm + t4 * 16 + lm;
                af[t4] = *(const bf16x8*)&cA[row * 64 + (((kh * 4 + qd) ^ (row & 7)) * 8)];
            }
#pragma unroll
            for (int j = 0; j < 2; ++j) {
                int col = wn + j * 16 + lm;
                bfr[j] = *(const bf16x8*)&cB[col * 64 + (((kh * 4 + qd) ^ (col & 7)) * 8)];
            }
#pragma unroll
            for (int ti = 0; ti < 4; ++ti)
#pragma unroll
                for (int tj = 0; tj < 2; ++tj)
                    acc[ti][tj] = mfma32(af[ti], bfr[tj], acc[ti][tj]);
        }
        if (t + 1 < 16) {
            asm volatile("s_waitcnt vmcnt(2)" ::: "memory");  // A(t+1) regs ready
            A_WRITE((t + 1) & 1);
        }
        asm volatile("s_waitcnt lgkmcnt(0)" ::: "memory");
        __builtin_amdgcn_s_barrier();
    }

    int head0 = n0 >> 6;                       // even head index
    int quad = wid >> 1;                       // col-quad 0..3 (32 cols each)
    int chead = wn & 63;                       // col base within head (0 or 32)

    if (head0 < 20) {
        int head = head0 + (quad >> 1);        // this wave's head
        bool isq = head < 16;
        const float* gvec = isq ? gq : gk;
        float gam[2];
#pragma unroll
        for (int tj = 0; tj < 2; ++tj) gam[tj] = gvec[chead + tj * 16 + lm];

        // partial row-sums of squares over this wave's 32 cols
#pragma unroll
        for (int ti = 0; ti < 4; ++ti)
#pragma unroll
            for (int r = 0; r < 4; ++r) {
                float sq = acc[ti][0][r] * acc[ti][0][r] + acc[ti][1][r] * acc[ti][1][r];
                sq += __shfl_xor(sq, 1);
                sq += __shfl_xor(sq, 2);
                sq += __shfl_xor(sq, 4);
                sq += __shfl_xor(sq, 8);
                if (lm == 0) ssp[quad][wm + ti * 16 + qd * 4 + r] = sq;
            }
        __syncthreads();

#pragma unroll
        for (int ti = 0; ti < 4; ++ti)
#pragma unroll
            for (int r = 0; r < 4; ++r) {
                int row = wm + ti * 16 + qd * 4 + r;
                int t = m0 + row;
                int pos = t & 2047, bb = t >> 11;
                float ss = ssp[quad][row] + ssp[quad ^ 1][row];
                float scale = rsqrtf(ss * (1.0f / 64.0f) + 1e-6f);
#pragma unroll
                for (int tj = 0; tj < 2; ++tj) {
                    int cw = chead + tj * 16 + lm;   // col within head
                    float v = acc[ti][tj][r] * scale * gam[tj];
                    float2 cs = rope_tab[pos * 32 + (cw >> 1)];
                    float pv = __shfl_xor(v, 1);
                    float outv = (cw & 1) ? (pv * cs.y + v * cs.x) : (v * cs.x - pv * cs.y);
                    if (isq) {
                        int kvh = head >> 2, h4 = head & 3;
                        size_t off = (((((size_t)bb * 4 + kvh) * 128 + (pos >> 4)) * 4 + h4) * 16
                                      + (pos & 15)) * 64 + cw;
                        Qb[off] = to_bf16(outv * 0.125f);
                    } else {
                        int kvg = head - 16;
                        Kbl[(((size_t)bb * 4 + kvg) * 2048 + pos) * 64 + cw] = to_bf16(outv);
                    }
                }
            }
    } else {
        // V: transpose both heads to [d][tok] via reused GEMM LDS (64KB free)
        __bf16* tvh = smem + (quad >> 1) * 8704;   // 64 x 136 per head
        int bb = m0 >> 11, pos0 = m0 & 2047;
#pragma unroll
        for (int ti = 0; ti < 4; ++ti)
#pragma unroll
            for (int tj = 0; tj < 2; ++tj)
#pragma unroll
                for (int r = 0; r < 4; ++r) {
                    int row = wm + ti * 16 + qd * 4 + r;
                    int cw = chead + tj * 16 + lm;
                    tvh[cw * 136 + row] = to_bf16(acc[ti][tj][r]);
                }
        __syncthreads();
        int hh = tid >> 8, t8 = tid & 255;
        int kvg = head0 + hh - 20;
        size_t gg = (size_t)bb * 4 + kvg;
        const __bf16* tvr = smem + hh * 8704;
#pragma unroll
        for (int p = 0; p < 4; ++p) {
            int d = p * 16 + (t8 >> 4);
            int tok = (t8 & 15) * 8;
            bf16x8 vvv = *(const bf16x8*)&tvr[d * 136 + tok];
            *(bf16x8*)(Vt + (gg * 64 + d) * 2048 + pos0 + tok) = vvv;
        }
    }
}

// ------- output projection GEMM: 512 thr, 8 waves (4m x 2n), 128x64 tile,
//         swizzled LDS, pre-swizzled gload sources, acc[2][2] ----------------
// LDS/buf: A 8192 + B 4096 bf16 = 24KB; x2 = 48KB dynamic. 512 blocks, 2/CU.
__global__ __launch_bounds__(512, 4) void gemm_op_k(const __bf16* __restrict__ A,
                                                    const __bf16* __restrict__ BT,
                                                    float* __restrict__ C) {
    extern __shared__ char smem_raw[];
    __bf16* smem = (__bf16*)smem_raw;
    int tid = threadIdx.x;
    int m0 = blockIdx.x * 128, n0 = blockIdx.y * 64;
    int wid = tid >> 6, lane = tid & 63;
    int wm = (wid & 3) * 32, wn = (wid >> 2) * 32;
    int lm = lane & 15, qd = lane >> 4;
    f32x4 acc[2][2] = {};
    auto STAGE = [&](int bsel, int t) {
        __bf16* base = smem + bsel * 12288;
#pragma unroll
        for (int r = 0; r < 2; ++r) {            // A: rows (tid>>3)+r*64
            int row = r * 64 + (tid >> 3);
            int c8 = (tid & 7) ^ (row & 7);
            gload_lds16(A + (size_t)(m0 + row) * 1024 + t * 64 + c8 * 8,
                        base + r * 4096 + wid * 512);
        }
        {                                        // B: rows tid>>3 (0..63)
            int row = tid >> 3;
            int c8 = (tid & 7) ^ (row & 7);
            gload_lds16(BT + (size_t)(n0 + row) * 1024 + t * 64 + c8 * 8,
                        base + 8192 + wid * 512);
        }
    };
    STAGE(0, 0);
    for (int t = 0; t < 16; ++t) {
        if (t + 1 < 16) {
            STAGE((t + 1) & 1, t + 1);
            asm volatile("s_waitcnt vmcnt(3)" ::: "memory");
        } else {
            asm volatile("s_waitcnt vmcnt(0)" ::: "memory");
        }
        __builtin_amdgcn_s_barrier();
        __builtin_amdgcn_sched_barrier(0);
        const __bf16* cA = smem + (t & 1) * 12288;
        const __bf16* cB = cA + 8192;
#pragma unroll
        for (int kh = 0; kh < 2; ++kh) {
            bf16x8 af[2], bfr[2];
#pragma unroll
            for (int i = 0; i < 2; ++i) {
                int row = wm + i * 16 + lm;
                af[i] = *(const bf16x8*)&cA[row * 64 + (((kh * 4 + qd) ^ (row & 7)) * 8)];
                int col = wn + i * 16 + lm;
                bfr[i] = *(const bf16x8*)&cB[col * 64 + (((kh * 4 + qd) ^ (col & 7)) * 8)];
            }
#pragma unroll
            for (int ti = 0; ti < 2; ++ti)
#pragma unroll
                for (int tj = 0; tj < 2; ++tj)
                    acc[ti][tj] = mfma32(af[ti], bfr[tj], acc[ti][tj]);
        }
        asm volatile("s_waitcnt lgkmcnt(0)" ::: "memory");
        __builtin_amdgcn_s_barrier();
    }
#pragma unroll
    for (int ti = 0; ti < 2; ++ti)
#pragma unroll
        for (int tj = 0; tj < 2; ++tj)
#pragma unroll
            for (int r = 0; r < 4; ++r) {
                int row = m0 + wm + ti * 16 + qd * 4 + r;
                int col = n0 + wn + tj * 16 + lm;
                C[(size_t)row * 1024 + col] = acc[ti][tj][r];
            }
}

// ---------------- MFMA flash attention, 32-query blocks, 8 waves ----------------
__global__ __launch_bounds__(512, 4) void attn_k(const __bf16* __restrict__ Qb,
                                                 const __bf16* __restrict__ Kbl,
                                                 const __bf16* __restrict__ Vt,
                                                 __bf16* __restrict__ aout) {
    __shared__ __bf16 Kt[2][64 * 64];   // [key][dim], swizzled
    __shared__ __bf16 Vl[2][64 * 64];   // [dim][key], swizzled
    int tid = threadIdx.x, wid = tid >> 6, lane = tid & 63;
    int l15 = lane & 15, quad = lane >> 4;
    int qb = blockIdx.x, kvh = blockIdx.y, b = blockIdx.z;
    int qg = wid >> 2;                  // query group 0/1
    int h4 = wid & 3;                   // head within group
    int iw0 = qb * 32;                  // block query base
    int iw = iw0 + qg * 16;             // wave query base
    int g = b * 4 + kvh;
    int h = kvh * 4 + h4;
    int e7 = l15 & 7;

    // Q^T B-frag straight from Qb (bf16, 1/8 pre-baked)
    int qbi = qb * 2 + qg;
    const __bf16* qp = Qb + ((((size_t)g * 128 + qbi) * 4 + h4) * 16 + l15) * 64 + quad * 8;
    bf16x8 qf0 = *(const bf16x8*)qp;
    bf16x8 qf1 = *(const bf16x8*)(qp + 32);

    int ts = (iw0 - 256) >> 6; if (ts < 1) ts = 1;
    int tmaxb = (iw0 + 31) >> 6;                       // block tile bound
    int n_all = (tmaxb >= ts) ? (tmaxb - ts + 2) : 1;  // [0] ++ [ts..tmaxb]
    int tmaxw = (iw + 15) >> 6;                        // wave mask bound

    const __bf16* Kg = Kbl + (size_t)g * 2048 * 64;
    const __bf16* Vg = Vt + (size_t)g * 64 * 2048;

    // staging: 512 threads, 1 K-chunk + 1 V-chunk of 8 elems each
    int r0 = tid >> 3, c0 = tid & 7;                   // rows 0..63
    int kl = r0 * 64 + ((c0 ^ (r0 & 7)) * 8);

    bf16x8 kr, vr;
    auto stage_load = [&](int tt) {
        kr = *(const bf16x8*)(Kg + (size_t)tt * 64 * 64 + r0 * 64 + c0 * 8);
        vr = *(const bf16x8*)(Vg + (size_t)r0 * 2048 + tt * 64 + c0 * 8);
    };
    auto stage_write = [&](int buf) {
        *(bf16x8*)&Kt[buf][kl] = kr;
        *(bf16x8*)&Vl[buf][kl] = vr;
    };

    stage_load(0);
    stage_write(0);

    f32x4 o[4] = {};
    float mr = -1e30f, lrp = 0.f;
    int iq = iw + l15;

    for (int idx = 0; idx < n_all; ++idx) {
        int tt = (idx == 0) ? 0 : ts + idx - 1;
        if (idx + 1 < n_all) stage_load(ts + idx);
        __syncthreads();
        int buf = idx & 1;

        // QK^T: S^T (C layout: row=key=nt*16+quad*4+r, col=query=l15)
        f32x4 s[4] = {};
#pragma unroll
        for (int nt = 0; nt < 4; ++nt) {
            const __bf16* kp = &Kt[buf][(nt * 16 + l15) * 64];
            bf16x8 k0 = *(const bf16x8*)(kp + ((quad ^ e7) * 8));
            bf16x8 k1 = *(const bf16x8*)(kp + (((quad + 4) ^ e7) * 8));
            s[nt] = mfma32(k0, qf0, s[nt]);
            s[nt] = mfma32(k1, qf1, s[nt]);
        }

        bool need_mask = (tt >= tmaxw) || (tt >= 1 && tt * 64 < iw + 15 - 256);
        if (need_mask) {
#pragma unroll
            for (int nt = 0; nt < 4; ++nt)
#pragma unroll
                for (int r = 0; r < 4; ++r) {
                    int j = tt * 64 + nt * 16 + quad * 4 + r;
                    bool valid = (j <= iq) && ((j >= iq - 256) || (j < 64));
                    s[nt][r] = valid ? s[nt][r] : -1e30f;
                }
        }

        float mx = -1e30f;
#pragma unroll
        for (int nt = 0; nt < 4; ++nt)
#pragma unroll
            for (int r = 0; r < 4; ++r) mx = fmaxf(mx, s[nt][r]);
        mx = fmaxf(mx, __shfl_xor(mx, 16));
        mx = fmaxf(mx, __shfl_xor(mx, 32));
        float mn = fmaxf(mr, mx);
        float alpha = __expf(mr - mn);
        mr = mn;

        float ps = 0.f;
        bf16x4 pb[4];
#pragma unroll
        for (int nt = 0; nt < 4; ++nt)
#pragma unroll
            for (int r = 0; r < 4; ++r) {
                float pv = __expf(s[nt][r] - mn);
                ps += pv;
                pb[nt][r] = to_bf16(pv);
            }
        lrp = lrp * alpha + ps;

        // PV: A = V^T frag from LDS, B = P^T (register-direct)
#pragma unroll
        for (int dt = 0; dt < 4; ++dt) {
            o[dt] *= alpha;
            const __bf16* vp = &Vl[buf][(dt * 16 + l15) * 64];
#pragma unroll
            for (int nt = 0; nt < 4; ++nt) {
                int c8 = 2 * nt + (quad >> 1);
                bf16x4 va = *(const bf16x4*)(vp + ((c8 ^ e7) * 8) + (quad & 1) * 4);
                o[dt] = mfma16(va, pb[nt], o[dt]);
            }
        }

        if (idx + 1 < n_all) stage_write((idx + 1) & 1);
    }

    // epilogue: reduce l across quads, normalize, LDS transpose, 16B stores
    lrp += __shfl_xor(lrp, 16);
    lrp += __shfl_xor(lrp, 32);
    float inv = 1.f / lrp;
    __syncthreads();                            // done with Kt/Vl buffers
    __bf16* pr = (__bf16*)Kt + wid * 16 * 64;   // 8 waves x 1024 elems = 16 KB
#pragma unroll
    for (int dt = 0; dt < 4; ++dt)
#pragma unroll
        for (int r = 0; r < 4; ++r) {
            int e = dt * 16 + quad * 4 + r;
            int c8 = e >> 3;
            pr[l15 * 64 + ((c8 ^ e7) * 8) + (e & 7)] = to_bf16(o[dt][r] * inv);
        }
    bf16x8 o0 = *(const bf16x8*)(pr + l15 * 64 + (((2 * quad) ^ e7) * 8));
    bf16x8 o1 = *(const bf16x8*)(pr + l15 * 64 + (((2 * quad + 1) ^ e7) * 8));
    __bf16* op = aout + ((size_t)b * 2048 + iw + l15) * 1024 + h * 64 + quad * 16;
    *(bf16x8*)op = o0;
    *(bf16x8*)(op + 8) = o1;
}

// ---------------- launch ----------------
extern "C" void kernel_launch(void* const* d_in, const int* in_sizes, int n_in,
                              void* d_out, int out_size, void* d_ws, size_t ws_size,
                              hipStream_t stream) {
    const float* x  = (const float*)d_in[0];
    const float* wq = (const float*)d_in[1];
    const float* wk = (const float*)d_in[2];
    const float* wv = (const float*)d_in[3];
    const float* wo = (const float*)d_in[4];
    const float* gq = (const float*)d_in[5];
    const float* gk = (const float*)d_in[6];
    float* out = (float*)d_out;

    char* ws = (char*)d_ws;
    __bf16*  WqkvT = (__bf16*)ws;                        //  3145728 B
    __bf16*  WoT   = (__bf16*)(ws + 3145728);            //  2097152 B
    __bf16*  aout  = (__bf16*)(ws + 5242880);            //  8388608 B (attn output)
    __bf16*  Kbl   = (__bf16*)(ws + 13631488);           //  2097152 B
    __bf16*  Vt    = (__bf16*)(ws + 15728640);           //  2097152 B
    __bf16*  Qb    = (__bf16*)(ws + 17825792);           //  8388608 B
    float2*  rtab  = (float2*)(ws + 26214400);           //   524288 B -> total 26738688

    prep_k<<<1792, dim3(256), 0, stream>>>(wq, wk, wv, WqkvT, rtab);
    gemmqkv_k<<<dim3(32, 16), dim3(512), 65536, stream>>>(x, WqkvT, rtab, gq, gk, wo,
                                                          Qb, Kbl, Vt, WoT);
    attn_k<<<dim3(64, 4, 2), dim3(512), 0, stream>>>(Qb, Kbl, Vt, aout);
    gemm_op_k<<<dim3(32, 16), dim3(512), 49152, stream>>>(aout, WoT, out);
}